// Round 1
// baseline (151.835 us; speedup 1.0000x reference)
//
#include <hip/hip_runtime.h>

typedef short s16x8 __attribute__((ext_vector_type(8)));
typedef short s16x4 __attribute__((ext_vector_type(4)));
typedef float f32x4 __attribute__((ext_vector_type(4)));
typedef float f4 __attribute__((ext_vector_type(4)));
typedef unsigned short u16x4 __attribute__((ext_vector_type(4)));

#define CEXP 14.426950408889634074f   // 10 * log2(e)

__device__ __forceinline__ unsigned short f2bf(float f) {
    union { float f; unsigned int i; } v; v.f = f;
    unsigned int x = v.i;
    return (unsigned short)((x + 0x7fffu + ((x >> 16) & 1u)) >> 16);  // RNE
}
__device__ __forceinline__ float bf2f(unsigned short u) {
    union { unsigned int i; float f; } v; v.i = ((unsigned int)u) << 16; return v.f;
}

__device__ __forceinline__ f32x4 mfma16x16x16_bf16(s16x4 a, s16x4 b, f32x4 c) {
#if __has_builtin(__builtin_amdgcn_mfma_f32_16x16x16bf16_1k)
    return __builtin_amdgcn_mfma_f32_16x16x16bf16_1k(a, b, c, 0, 0, 0);
#else
    f32x4 d = c;
    asm("v_mfma_f32_16x16x16_bf16 %0, %1, %2, %0" : "+v"(d) : "v"(a), "v"(b));
    return d;
#endif
}

// pack 4 fp32 -> 4 bf16 (element order preserved)
__device__ __forceinline__ s16x4 pk_bf16x4(float p0, float p1, float p2, float p3) {
#if __has_builtin(__builtin_amdgcn_cvt_pk_bf16_f32)
    typedef __bf16 bf16x2 __attribute__((ext_vector_type(2)));
    union { struct { bf16x2 a, b; } h; s16x4 s; } r;
    r.h.a = __builtin_amdgcn_cvt_pk_bf16_f32(p0, p1);
    r.h.b = __builtin_amdgcn_cvt_pk_bf16_f32(p2, p3);
    return r.s;
#else
    unsigned u0 = __float_as_uint(p0) + 0x8000u;
    unsigned u1 = __float_as_uint(p1) + 0x8000u;
    unsigned u2 = __float_as_uint(p2) + 0x8000u;
    unsigned u3 = __float_as_uint(p3) + 0x8000u;
    union { uint2 u; s16x4 s; } pb;
    pb.u.x = __builtin_amdgcn_perm(u1, u0, 0x07060302u);
    pb.u.y = __builtin_amdgcn_perm(u3, u2, 0x07060302u);
    return pb.s;
#endif
}

__device__ __forceinline__ u16x4 pk4(f4 v) {
    u16x4 r = { f2bf(v[0]), f2bf(v[1]), f2bf(v[2]), f2bf(v[3]) };
    return r;
}

// ---------------------------------------------------------------------------
// k_prep v2 (unchanged): coalesced 64x64 LDS-tile transposes.
// ---------------------------------------------------------------------------
__global__ __launch_bounds__(256) void k_prep(
    const float* __restrict__ Wqkv, const float* __restrict__ Wout,
    unsigned short* __restrict__ Wt, unsigned short* __restrict__ WoT,
    float* __restrict__ sumsqp)
{
    __shared__ float tile[64][65];
    const int blk = blockIdx.x, tid = threadIdx.x;
    if (blk >= 16) {
        sumsqp[(blk - 16) * 256 + tid] = 0.f;     // 32 blocks x 256 = 8192
        return;
    }
    const float* src;
    unsigned short* dst;
    int lds_src, k0, n0;
    if (blk < 12) {
        src = Wqkv; dst = Wt; lds_src = 384;
        k0 = (blk & 1) * 64; n0 = (blk >> 1) * 64;
    } else {
        int b = blk - 12;
        src = Wout; dst = WoT; lds_src = 128;
        k0 = (b & 1) * 64; n0 = (b >> 1) * 64;
    }
    const int c = tid & 63, r0 = tid >> 6;
#pragma unroll
    for (int i = 0; i < 16; ++i) {
        int row = i * 4 + r0;
        tile[row][c] = src[(size_t)(k0 + row) * lds_src + n0 + c];
    }
    __syncthreads();
#pragma unroll
    for (int i = 0; i < 16; ++i) {
        int n = i * 4 + r0;
        dst[(size_t)(n0 + n) * 128 + k0 + c] = f2bf(tile[c][n]);
    }
}

// ---------------------------------------------------------------------------
// k_qkv v6 (unchanged).
// ---------------------------------------------------------------------------
__global__ __launch_bounds__(256, 2) void k_qkv(
    const float* __restrict__ x, const unsigned short* __restrict__ Wt,
    unsigned short* __restrict__ Qb, unsigned short* __restrict__ Kb,
    unsigned short* __restrict__ Vt, float* __restrict__ sumsqp)
{
    __shared__ float red[4][64];
    const int tid = threadIdx.x;
    const int wl = tid >> 6, lane = tid & 63;
    const int qd = lane >> 4, nn = lane & 15;
    const int n0 = blockIdx.y * 64;            // global output col base
    const int tw0 = blockIdx.x * 64 + wl * 16; // token base for this wave

    const float* apf = x + (size_t)(tw0 + nn) * 128 + qd * 8;
    const unsigned short* bp = Wt + (size_t)(n0 + nn) * 128 + qd * 8;
    s16x8 af[4], bfr[16];
#pragma unroll
    for (int ks = 0; ks < 4; ++ks) {
        f4 a0 = *(const f4*)(apf + ks * 32);
        f4 a1 = *(const f4*)(apf + ks * 32 + 4);
        union { struct { s16x4 lo, hi; } h; s16x8 v; } u;
        u.h.lo = pk_bf16x4(a0[0], a0[1], a0[2], a0[3]);
        u.h.hi = pk_bf16x4(a1[0], a1[1], a1[2], a1[3]);
        af[ks] = u.v;
    }
#pragma unroll
    for (int nb = 0; nb < 4; ++nb)
#pragma unroll
        for (int ks = 0; ks < 4; ++ks)
            bfr[nb * 4 + ks] = *(const s16x8*)(bp + (size_t)nb * 2048 + ks * 32);

    f32x4 acc[4];
#pragma unroll
    for (int nb = 0; nb < 4; ++nb) acc[nb] = (f32x4){0.f, 0.f, 0.f, 0.f};

    const int cb = n0 >> 7;            // 0=q 1=k 2=v
    const int b = tw0 >> 12;           // batch (block-uniform: 64 | 4096)
    const int tl0 = tw0 & 4095;        // token within batch

    if (cb < 2) {
        // A = W rows (out-cols), B = x rows (tokens)
#pragma unroll
        for (int ks = 0; ks < 4; ++ks)
#pragma unroll
            for (int nb = 0; nb < 4; ++nb)
                acc[nb] = __builtin_amdgcn_mfma_f32_16x16x32_bf16(bfr[nb * 4 + ks], af[ks], acc[nb], 0, 0, 0);
        unsigned short* dst = (cb == 0) ? Qb : Kb;
        const int tok = tl0 + nn;
#pragma unroll
        for (int nb = 0; nb < 4; ++nb) {
            const int dim = (n0 & 127) + nb * 16 + qd * 4;   // 4-aligned, +r
            const int h = dim >> 5, d0 = dim & 31;
            *(u16x4*)&dst[(size_t)((b * 4 + h) * 4096 + tok) * 32 + d0] = pk4(acc[nb]);
            f32x4 ss;
#pragma unroll
            for (int r = 0; r < 4; ++r) ss[r] = acc[nb][r] * acc[nb][r];
#pragma unroll
            for (int m = 1; m < 16; m <<= 1) {
#pragma unroll
                for (int r = 0; r < 4; ++r) ss[r] += __shfl_xor(ss[r], m);
            }
            if (nn == 0)
                *(f4*)&red[wl][nb * 16 + qd * 4] = ss;   // slab partial, this wave
        }
        __syncthreads();                       // block-uniform branch: safe
        if (tid < 64) {
            float s = red[0][tid] + red[1][tid] + red[2][tid] + red[3][tid];
            const int g = (cb << 9) + (b << 7) + (n0 & 127) + tid;
            atomicAdd(&sumsqp[((blockIdx.x & 7) << 10) + g], s);
        }
    } else {
        // A = x rows (tokens), B = W rows (out-cols): D row = token = 4qd+r
#pragma unroll
        for (int ks = 0; ks < 4; ++ks)
#pragma unroll
            for (int nb = 0; nb < 4; ++nb)
                acc[nb] = __builtin_amdgcn_mfma_f32_16x16x32_bf16(af[ks], bfr[nb * 4 + ks], acc[nb], 0, 0, 0);
#pragma unroll
        for (int nb = 0; nb < 4; ++nb) {
            const int dim = (n0 & 127) + nb * 16 + nn;
            const int h = dim >> 5, d = dim & 31;
            *(u16x4*)&Vt[(size_t)((b * 4 + h) * 32 + d) * 4096 + tl0 + qd * 4] = pk4(acc[nb]);
        }
    }
}

// ---------------------------------------------------------------------------
// k_attn v8: i-span per wave 32 -> 64 (4 Q tiles, 8 O + 4 l accumulators).
// Rationale (R12 rocprof): LDS unit was the top pipe (~29 us busy vs ~21 us
// MFMA; all 4 waves of a j-half re-read the same K/V tiles -> 1.07 GB LDS
// reads).  Doubling i-span halves wave count and LDS read traffic; MFMA and
// exp totals unchanged.  Blocks shrink to 256 thr (2 i-groups x 2 j-halves),
// grid stays (16,32) -> 2 blocks/CU = 2 independent barrier groups.
// Staging: each wave now stages 2 KB K + 2 KB V per jt (4 uint4 loads,
// 4 ds_write_b128), same aggregate as v7.  Layouts/patterns preserved.
// ---------------------------------------------------------------------------
__global__ __launch_bounds__(256, 2) void k_attn(
    const unsigned short* __restrict__ Qb, const unsigned short* __restrict__ Kb,
    const unsigned short* __restrict__ Vt, const float* __restrict__ sumsqp,
    unsigned short* __restrict__ Ogb)
{
    __shared__ char smem[32768];
    const int tid  = threadIdx.x;
    const int wv   = tid >> 6, lane = tid & 63;
    const int ig   = wv & 1, half = wv >> 1;   // i-group, j-half
    const int qd   = lane >> 4, nn = lane & 15;
    const int bh   = blockIdx.x;
    const int ib   = blockIdx.y * 128 + ig * 64;
    const unsigned short* Qbh = Qb + (size_t)bh * 4096 * 32;
    const unsigned short* Kbh = Kb + (size_t)bh * 4096 * 32;
    const unsigned short* Vbh = Vt + (size_t)bh * 32 * 4096;

    // rj[d] = min(rsqrt(ssq_q),1e12) * min(rsqrt(ssq_k),1e12) * CEXP
    float rj[8];
    {
        const int gq = bh * 32 + qd * 8;
#pragma unroll
        for (int j = 0; j < 8; ++j) {
            float sq = 0.f, sk = 0.f;
#pragma unroll
            for (int c = 0; c < 8; ++c) {
                sq += sumsqp[c * 1024 + gq + j];
                sk += sumsqp[c * 1024 + 512 + gq + j];
            }
            rj[j] = fminf(__builtin_amdgcn_rsqf(sq), 1e12f)
                  * fminf(__builtin_amdgcn_rsqf(sk), 1e12f) * CEXP;
        }
    }

    // 4 Q tiles (i = ib + t*16 + nn), rq*rk*CEXP folded per-d into qf
    s16x8 qf[4];
#pragma unroll
    for (int t = 0; t < 4; ++t) {
        s16x8 qr = *(const s16x8*)(Qbh + (size_t)(ib + t * 16 + nn) * 32 + qd * 8);
        s16x8 qs;
#pragma unroll
        for (int j = 0; j < 8; ++j)
            qs[j] = (short)f2bf(bf2f((unsigned short)qr[j]) * rj[j]);
        qf[t] = qs;
    }

    f32x4 o[4][2], l[4];
#pragma unroll
    for (int t = 0; t < 4; ++t) {
        o[t][0] = (f32x4){0.f,0.f,0.f,0.f};
        o[t][1] = (f32x4){0.f,0.f,0.f,0.f};
        l[t]    = (f32x4){0.f,0.f,0.f,0.f};
    }
    const f32x4 zro = {0.f,0.f,0.f,0.f};
    const s16x4 ones1 = { (short)0x3F80, (short)0x3F80, (short)0x3F80, (short)0x3F80 };

    const int KB0 = half * 8192;           // K dbuf: 2 x 4KB per half
    const int VB0 = 16384 + half * 8192;   // V dbuf: 2 x 4KB per half
    const int jb0 = half * 2048;

    // this wave stages chunks {2*ig, 2*ig+1} of the 4x1KB half-tile
    const unsigned short* ksrc = Kbh + (size_t)(jb0 + ig * 32 + nn) * 32 + qd * 8;
    const unsigned short* vsrc = Vbh + (size_t)(nn + 16 * ig) * 4096
                               + jb0 + (qd >> 1) * 16 + (qd & 1) * 8;
    char* kdst = smem + KB0 + ig * 2048 + lane * 16;
    char* vdst = smem + VB0 + ig * 2048 + lane * 16;

    {   // preload tile 0 -> buffer 0
        uint4 gk0 = *(const uint4*)ksrc;
        uint4 gk1 = *(const uint4*)(ksrc + 512);   // +16 j rows
        uint4 gv0 = *(const uint4*)vsrc;
        uint4 gv1 = *(const uint4*)(vsrc + 32);    // +32 j (second j32 group)
        ksrc += 2048; vsrc += 64;
        *(uint4*)kdst = gk0;  *(uint4*)(kdst + 1024) = gk1;
        *(uint4*)vdst = gv0;  *(uint4*)(vdst + 1024) = gv1;
    }

    const int vro = (qd >> 1) * 256 + nn * 16 + (qd & 1) * 8;

    for (int jt = 0; jt < 32; ++jt) {
        uint4 ngk0 = *(const uint4*)ksrc;          // tile jt+1 (jt=31: in-ws, unused)
        uint4 ngk1 = *(const uint4*)(ksrc + 512);
        uint4 ngv0 = *(const uint4*)vsrc;
        uint4 ngv1 = *(const uint4*)(vsrc + 32);
        ksrc += 2048; vsrc += 64;

        __syncthreads();
        const char* kcur = smem + KB0 + (jt & 1) * 4096;
        const char* vcur = smem + VB0 + (jt & 1) * 4096;
#pragma unroll
        for (int js = 0; js < 4; ++js) {
            s16x8 kf = *(const s16x8*)(kcur + js * 1024 + lane * 16);
            s16x4 va = *(const s16x4*)(vcur + js * 512 + vro);
            s16x4 vb = *(const s16x4*)(vcur + 2048 + js * 512 + vro);
#pragma unroll
            for (int t = 0; t < 4; ++t) {
                f32x4 s = __builtin_amdgcn_mfma_f32_16x16x32_bf16(kf, qf[t], zro, 0, 0, 0);
                float e0 = __builtin_amdgcn_exp2f(s[0]);
                float e1 = __builtin_amdgcn_exp2f(s[1]);
                float e2 = __builtin_amdgcn_exp2f(s[2]);
                float e3 = __builtin_amdgcn_exp2f(s[3]);
                s16x4 p = pk_bf16x4(e0, e1, e2, e3);
                l[t]    = mfma16x16x16_bf16(ones1, p, l[t]);   // row-sums of P (i = col = nn)
                o[t][0] = mfma16x16x16_bf16(va, p, o[t][0]);
                o[t][1] = mfma16x16x16_bf16(vb, p, o[t][1]);
            }
        }
        const int nxt4k = ((jt + 1) & 1) * 4096;
        *(uint4*)(kdst + nxt4k) = ngk0;  *(uint4*)(kdst + nxt4k + 1024) = ngk1;
        *(uint4*)(vdst + nxt4k) = ngv0;  *(uint4*)(vdst + nxt4k + 1024) = ngv1;
    }

    __syncthreads();                           // staging LDS dead now
    float* Ob = (float*)smem;                  // [2 ig][4 t][64 lane][8] = 16KB
    float* Lb = (float*)(smem + 16384);        // [2][4][64] = 2KB
    if (half) {
#pragma unroll
        for (int t = 0; t < 4; ++t) {
            float* d = Ob + (size_t)((ig * 4 + t) * 64 + lane) * 8;
            *(f4*)d = o[t][0]; *(f4*)(d + 4) = o[t][1];
            Lb[(ig * 4 + t) * 64 + lane] = l[t][0];
        }
    }
    __syncthreads();
    if (!half) {
        const int bb = bh >> 2, hh = bh & 3;
#pragma unroll
        for (int t = 0; t < 4; ++t) {
            float* s = Ob + (size_t)((ig * 4 + t) * 64 + lane) * 8;
            float rl = 1.f / (l[t][0] + Lb[(ig * 4 + t) * 64 + lane]);
            f4 m0v = (o[t][0] + *(const f4*)s) * rl;
            f4 m1v = (o[t][1] + *(const f4*)(s + 4)) * rl;
            unsigned short* dst = Ogb
                + (size_t)(bb * 4096 + blockIdx.y * 128 + ig * 64 + t * 16 + nn) * 128
                + hh * 32 + qd * 4;
            *(u16x4*)dst = pk4(m0v);
            *(u16x4*)(dst + 16) = pk4(m1v);
        }
    }
}

// ---------------------------------------------------------------------------
// k_out (unchanged): out = Og @ W_out + b_out.
// ---------------------------------------------------------------------------
__global__ __launch_bounds__(256, 2) void k_out(
    const unsigned short* __restrict__ Ogb, const unsigned short* __restrict__ WoT,
    const float* __restrict__ bout, float* __restrict__ out)
{
    const int tid = threadIdx.x;
    const int wl = tid >> 6, lane = tid & 63;
    const int qd = lane >> 4, nn = lane & 15;
    const int n0 = blockIdx.y * 64;            // outc base
    const int tw0 = blockIdx.x * 64 + wl * 16; // token base

    const unsigned short* ap = WoT + (size_t)(n0 + nn) * 128 + qd * 8;
    const unsigned short* bp = Ogb + (size_t)(tw0 + nn) * 128 + qd * 8;
    s16x8 bfr[4], afr[16];
#pragma unroll
    for (int ks = 0; ks < 4; ++ks) bfr[ks] = *(const s16x8*)(bp + ks * 32);
#pragma unroll
    for (int nb = 0; nb < 4; ++nb)
#pragma unroll
        for (int ks = 0; ks < 4; ++ks)
            afr[nb * 4 + ks] = *(const s16x8*)(ap + (size_t)nb * 2048 + ks * 32);

    f32x4 acc[4];
#pragma unroll
    for (int nb = 0; nb < 4; ++nb) acc[nb] = (f32x4){0.f, 0.f, 0.f, 0.f};
#pragma unroll
    for (int ks = 0; ks < 4; ++ks)
#pragma unroll
        for (int nb = 0; nb < 4; ++nb)
            acc[nb] = __builtin_amdgcn_mfma_f32_16x16x32_bf16(afr[nb * 4 + ks], bfr[ks], acc[nb], 0, 0, 0);

#pragma unroll
    for (int nb = 0; nb < 4; ++nb) {
        const int c = n0 + nb * 16 + qd * 4;
        f4 bv = *(const f4*)&bout[c];
        f4 r;
#pragma unroll
        for (int j = 0; j < 4; ++j) r[j] = acc[nb][j] + bv[j];
        *(f4*)&out[(size_t)(tw0 + nn) * 128 + c] = r;
    }
}

// ---------------------------------------------------------------------------
extern "C" void kernel_launch(void* const* d_in, const int* in_sizes, int n_in,
                              void* d_out, int out_size, void* d_ws, size_t ws_size,
                              hipStream_t stream)
{
    const float* x    = (const float*)d_in[0];
    const float* Wqkv = (const float*)d_in[1];
    const float* Wout = (const float*)d_in[2];
    const float* bout = (const float*)d_in[3];
    float* out = (float*)d_out;
    char* ws = (char*)d_ws;
    const size_t MB = 1024 * 1024;
    unsigned short* Qb  = (unsigned short*)(ws);             // 4 MB [16][4096][32] (raw q)
    unsigned short* Kb  = (unsigned short*)(ws + 4 * MB);    // 4 MB (raw k)
    unsigned short* Vt  = (unsigned short*)(ws + 8 * MB);    // 4 MB [16][32][4096]
    unsigned short* Ogb = (unsigned short*)(ws + 12 * MB);   // 4 MB [16384][128] bf16
    unsigned short* Wt  = (unsigned short*)(ws + 16 * MB);               // 96 KB
    unsigned short* WoT = (unsigned short*)(ws + 16 * MB + 112 * 1024);  // 32 KB
    float*       sumsqp = (float*)(ws + 16 * MB + 160 * 1024);           // 32 KB [8][1024]

    hipLaunchKernelGGL(k_prep, dim3(48), dim3(256), 0, stream, Wqkv, Wout, Wt, WoT, sumsqp);
    hipLaunchKernelGGL(k_qkv, dim3(256, 6), dim3(256), 0, stream, x, Wt, Qb, Kb, Vt, sumsqp);
    hipLaunchKernelGGL(k_attn, dim3(16, 32), dim3(256), 0, stream, Qb, Kb, Vt, sumsqp, Ogb);
    hipLaunchKernelGGL(k_out, dim3(256, 2), dim3(256), 0, stream, Ogb, WoT, bout, out);
}